// Round 10
// baseline (408.637 us; speedup 1.0000x reference)
//
#include <hip/hip_runtime.h>
#include <hip/hip_bf16.h>
#include <math.h>

#define N_NODES 50000
#define N_EDGES 600000
#define EG 3750   // edge-kernel grid; blockA has EG+1 node-aligned edge offsets
// IN_DIM=128, EDGE_DIM=64; e = relu(U[src] + V[dst] + ef@We + b_pre)

typedef __attribute__((ext_vector_type(8))) short short8v;   // 8 bf16 MFMA A/B frag
typedef __attribute__((ext_vector_type(4))) short short4v;
typedef __attribute__((ext_vector_type(4))) float f32x4;     // MFMA C/D frag
typedef __attribute__((ext_vector_type(4))) float float4v;

#define FLT_BIG 3.402823466e38f

__device__ __forceinline__ short f2bf(float f) {
  unsigned int u = __float_as_uint(f);
  u = (u + 0x7FFFu + ((u >> 16) & 1u)) >> 16;   // RNE
  return (short)u;
}
__device__ __forceinline__ float bf2f(unsigned short s) {
  return __uint_as_float(((unsigned int)s) << 16);
}

// ---- weights (+ deg zeroing): WuvT[256][128], WeT[128][64], Wp1T, Wp2T -----
__global__ void conv_w_kernel(const float* __restrict__ Wpre, const float* __restrict__ Wp1,
                              const float* __restrict__ Wp2, short* __restrict__ WuvT,
                              short* __restrict__ WeT, short* __restrict__ Wp1T,
                              short* __restrict__ Wp2T, int* __restrict__ deg) {
  int idx = blockIdx.x * 256 + threadIdx.x;
  if (idx < 50048) deg[idx] = 0;
  if (idx < 32768) {                       // WuvT: row c (<128:U, >=128:V), col k
    int c = idx >> 7, k = idx & 127;
    WuvT[idx] = f2bf(Wpre[(k + ((c >> 7) << 7)) * 128 + (c & 127)]);
  } else if (idx < 40960) {                // WeT
    int o = idx - 32768, n = o >> 6, k = o & 63;
    WeT[o] = f2bf(Wpre[(256 + k) * 128 + n]);
  } else if (idx < 253952) {               // Wp1T
    int o = idx - 40960, n = o / 1664, k = o % 1664;
    Wp1T[o] = f2bf(Wp1[k * 128 + n]);
  } else if (idx < 270336) {               // Wp2T
    int o = idx - 253952, n = o >> 7, k = o & 127;
    Wp2T[o] = f2bf(Wp2[k * 128 + n]);
  }
}

// ---- degree histogram ------------------------------------------------------
__global__ void deg_kernel(const int* __restrict__ dst, int* __restrict__ deg) {
  int i = blockIdx.x * blockDim.x + threadIdx.x;
  int stride = gridDim.x * blockDim.x;
  for (; i < N_EDGES; i += stride) atomicAdd(deg + dst[i], 1);
}

// ---- exclusive scan of deg -> cursor + stable rowStart (N+1 w/ sentinel) ---
__global__ __launch_bounds__(1024) void scan_kernel(const int* __restrict__ deg,
                                                    int* __restrict__ cursor,
                                                    int* __restrict__ rowStart) {
  __shared__ int part[1024];
  const int CH = 49;
  int t = threadIdx.x;
  int base = t * CH;
  int s = 0;
  for (int i = 0; i < CH; i++) {
    int idx = base + i;
    if (idx < N_NODES) s += deg[idx];
  }
  part[t] = s;
  __syncthreads();
  for (int off = 1; off < 1024; off <<= 1) {
    int v = (t >= off) ? part[t - off] : 0;
    __syncthreads();
    part[t] += v;
    __syncthreads();
  }
  int ex = (t == 0) ? 0 : part[t - 1];
  for (int i = 0; i < CH; i++) {
    int idx = base + i;
    if (idx < N_NODES) {
      cursor[idx] = ex;
      rowStart[idx] = ex;
      ex += deg[idx];
    }
  }
  if (t == 0) rowStart[N_NODES] = N_EDGES;
}

// ---- scatter: eid int4{perm,src,dst,0} + node-aligned block ranges ---------
__global__ void scatter_kernel(const int* __restrict__ src, const int* __restrict__ dst,
                               int* __restrict__ cursor, const int* __restrict__ rowStart,
                               int4* __restrict__ eid, int* __restrict__ blockA) {
  int i0 = blockIdx.x * blockDim.x + threadIdx.x;
  int stride = gridDim.x * blockDim.x;
  for (int i = i0; i < N_EDGES; i += stride) {
    int d = dst[i];
    int pos = atomicAdd(cursor + d, 1);
    eid[pos] = make_int4(i, src[i], d, 0);
  }
  for (int j = N_EDGES + i0; j < N_EDGES + 64; j += stride)
    eid[j] = make_int4(0, 0, 0, 0);  // safe tail for clamped prefetch
  for (int b = i0; b <= EG; b += stride) {
    int tgt = (int)((long)b * N_EDGES / EG);
    int lo = 0, hi = N_NODES;
    while (lo < hi) { int mid = (lo + hi) >> 1; if (rowStart[mid] < tgt) lo = mid + 1; else hi = mid; }
    blockA[b] = rowStart[lo];   // node-aligned; rowStart[N]=E sentinel
  }
}

// ---- UV kernel: [U|V] = x @ [Ws|Wd], dense 50K x 128 -> 256, bf16 out ------
__global__ __launch_bounds__(256) void uv_kernel(const float* __restrict__ nf,
                                                 const short* __restrict__ WuvT,
                                                 short* __restrict__ UV) {
  __shared__ short A[64][136];
  int t = threadIdx.x;
  int lane = t & 63, w = t >> 6;
  int r15 = lane & 15, g = lane >> 4;
  int nb = blockIdx.x * 64;

#pragma unroll
  for (int i = 0; i < 8; i++) {
    int u = t + 256 * i, row = u >> 5, q = u & 31;
    int gn = min(nb + row, N_NODES - 1);
    float4v a = *(const float4v*)(nf + (size_t)gn * 128 + q * 4);
    short4v s;
    s[0] = f2bf(a[0]); s[1] = f2bf(a[1]); s[2] = f2bf(a[2]); s[3] = f2bf(a[3]);
    *(short4v*)(&A[row][q * 4]) = s;
  }
  __syncthreads();

  f32x4 acc[4][4];
#pragma unroll
  for (int m = 0; m < 4; m++)
#pragma unroll
    for (int j = 0; j < 4; j++) acc[m][j] = (f32x4){0.f, 0.f, 0.f, 0.f};

#pragma unroll
  for (int ks = 0; ks < 4; ks++) {
    short8v af[4];
#pragma unroll
    for (int m = 0; m < 4; m++) af[m] = *(const short8v*)(&A[m * 16 + r15][ks * 32 + 8 * g]);
#pragma unroll
    for (int j = 0; j < 4; j++) {
      short8v bf = *(const short8v*)(WuvT + (size_t)((4 * w + j) * 16 + r15) * 128 + ks * 32 + 8 * g);
#pragma unroll
      for (int m = 0; m < 4; m++)
        acc[m][j] = __builtin_amdgcn_mfma_f32_16x16x32_bf16(af[m], bf, acc[m][j], 0, 0, 0);
    }
  }

#pragma unroll
  for (int m = 0; m < 4; m++)
#pragma unroll
    for (int j = 0; j < 4; j++)
#pragma unroll
      for (int r = 0; r < 4; r++) {
        int node = nb + m * 16 + 4 * g + r;
        if (node < N_NODES)
          UV[(size_t)node * 256 + (4 * w + j) * 16 + r15] = f2bf(acc[m][j][r]);
      }
}

// ---- edge kernel: node-aligned block ranges, carry accumulators across -----
// chunks, ALL flushes plain stores (no atomics, no plane init needed).
__global__ __launch_bounds__(256, 6) void edge_kernel(
    const int4* __restrict__ eid, const int* __restrict__ blockA,
    const float* __restrict__ edge_feat, const float* __restrict__ b_pre,
    const short* __restrict__ UV, const short* __restrict__ WeT,
    float* __restrict__ sum, float* __restrict__ sq,
    float* __restrict__ mx, float* __restrict__ mn) {
  __shared__ short A[32][72];        // 32 edges x 64 k (pad 8)
  __shared__ float E[32][132];       // F, then in-place e (pad 4)
  __shared__ int srcL[2][32], dstL[2][32];

  int t = threadIdx.x;
  int lane = t & 63, w = t >> 6;
  int r15 = lane & 15, g = lane >> 4;

  short8v bfr[2][2];
#pragma unroll
  for (int ks = 0; ks < 2; ks++)
#pragma unroll
    for (int j = 0; j < 2; j++)
      bfr[ks][j] = *(const short8v*)(WeT + (size_t)((2 * w + j) * 16 + r15) * 64 + ks * 32 + 8 * g);

  int c = t & 127, half = t >> 7;    // scan role: col, stat-pair
  int cd = t & 63, wrow = t >> 6;    // compose role: col-pair, row-group
  float bp0 = b_pre[2 * cd], bp1 = b_pre[2 * cd + 1];

  const unsigned short* UVu = (const unsigned short*)UV;
  int A0 = blockA[blockIdx.x], A1 = blockA[blockIdx.x + 1];
  if (A0 >= A1) return;

  float4v ge[2];
  auto LOADE = [&](int e0c) {
#pragma unroll
    for (int i = 0; i < 2; i++) {
      int u = t + 256 * i, e = u >> 4, q = u & 15;
      int pe = eid[min(e0c + e, N_EDGES + 63)].x;
      ge[i] = *(const float4v*)(edge_feat + (size_t)pe * 64 + q * 4);
    }
  };
  auto WRITE_A = [&]() {
#pragma unroll
    for (int i = 0; i < 2; i++) {
      int u = t + 256 * i, e = u >> 4, q = u & 15;
      short4v s4;
      s4[0] = f2bf(ge[i][0]); s4[1] = f2bf(ge[i][1]);
      s4[2] = f2bf(ge[i][2]); s4[3] = f2bf(ge[i][3]);
      *(short4v*)(&A[e][q * 4]) = s4;
    }
  };
  int nsrc = 0, ndst = 0;
  auto IDXLOAD = [&](int e0c) {
    if (t < 32) {
      int4 v = eid[min(e0c + t, N_EDGES + 63)];
      nsrc = v.y; ndst = v.z;
    }
  };

  // prologue
  LOADE(A0);
  IDXLOAD(A0);
  if (t < 32) { srcL[0][t] = nsrc; dstL[0][t] = ndst; }
  WRITE_A();
  IDXLOAD(A0 + 32);
  __syncthreads();

  // carried segment state (node-aligned ownership -> plain stores only)
  float a0 = (half == 0) ? 0.f : -FLT_BIG;
  float a1 = (half == 0) ? 0.f : FLT_BIG;
  int prevd = -1;

  int p = 0;
  for (int e0 = A0; e0 < A1; e0 += 32) {
    int cnt = min(32, A1 - e0);
    // ==== P1: whole-chunk UV prefetch; MFMA F; issue next gathers ====
    unsigned int upf[8], vpf[8];
#pragma unroll
    for (int i = 0; i < 8; i++) {
      int rr = min(wrow + 4 * i, cnt - 1);
      int sr = srcL[p][rr], dr = dstL[p][rr];
      upf[i] = *(const unsigned int*)(UVu + (size_t)sr * 256 + 2 * cd);
      vpf[i] = *(const unsigned int*)(UVu + (size_t)dr * 256 + 128 + 2 * cd);
    }
    LOADE(e0 + 32);

    f32x4 acc[2][2];
#pragma unroll
    for (int m = 0; m < 2; m++)
#pragma unroll
      for (int j = 0; j < 2; j++) acc[m][j] = (f32x4){0.f, 0.f, 0.f, 0.f};
#pragma unroll
    for (int m = 0; m < 2; m++)
#pragma unroll
      for (int ks = 0; ks < 2; ks++) {
        short8v af = *(const short8v*)(&A[m * 16 + r15][ks * 32 + 8 * g]);
        acc[m][0] = __builtin_amdgcn_mfma_f32_16x16x32_bf16(af, bfr[ks][0], acc[m][0], 0, 0, 0);
        acc[m][1] = __builtin_amdgcn_mfma_f32_16x16x32_bf16(af, bfr[ks][1], acc[m][1], 0, 0, 0);
      }
#pragma unroll
    for (int m = 0; m < 2; m++)
#pragma unroll
      for (int j = 0; j < 2; j++)
#pragma unroll
        for (int r = 0; r < 4; r++)
          E[m * 16 + 4 * g + r][(2 * w + j) * 16 + r15] = acc[m][j][r];
    __syncthreads();  // B1

    // ==== P2a: e = relu(u + v + F + b) in place ====
#pragma unroll
    for (int i = 0; i < 8; i++) {
      int r = wrow + 4 * i;
      float u0 = bf2f((unsigned short)(upf[i] & 0xFFFFu));
      float u1 = bf2f((unsigned short)(upf[i] >> 16));
      float v0 = bf2f((unsigned short)(vpf[i] & 0xFFFFu));
      float v1 = bf2f((unsigned short)(vpf[i] >> 16));
      E[r][2 * cd] = fmaxf(u0 + v0 + E[r][2 * cd] + bp0, 0.f);
      E[r][2 * cd + 1] = fmaxf(u1 + v1 + E[r][2 * cd + 1] + bp1, 0.f);
    }
    __syncthreads();  // B2

    // ==== P2b: carried segmented scan, plain stores; stage next chunk ====
    {
      int l = lane & 31;
      int dl_ = dstL[p][l];
      int dp_ = (l == 0) ? prevd : dstL[p][l - 1];
      unsigned int bm = (unsigned int)__ballot(dl_ != dp_);
#pragma unroll
      for (int r = 0; r < 32; r++) {
        if (r < cnt) {  // uniform
          if ((bm >> r) & 1u) {  // wave-uniform
            int tgt = (r == 0) ? prevd : dstL[p][r - 1];
            if (tgt >= 0) {
              size_t o = (size_t)tgt * 128 + c;
              if (half == 0) { sum[o] = a0; sq[o] = a1; }
              else { mx[o] = a0; mn[o] = a1; }
            }
            if (half == 0) { a0 = 0.f; a1 = 0.f; }
            else { a0 = -FLT_BIG; a1 = FLT_BIG; }
          }
          float e = E[r][c];
          if (half == 0) { a0 += e; a1 += e * e; }
          else { a0 = fmaxf(a0, e); a1 = fminf(a1, e); }
        }
      }
      prevd = dstL[p][cnt - 1];
    }
    WRITE_A();
    if (t < 32) { srcL[p ^ 1][t] = nsrc; dstL[p ^ 1][t] = ndst; }
    IDXLOAD(e0 + 64);
    __syncthreads();  // B3
    p ^= 1;
  }
  // final flush of carried segment (block owns this node exclusively)
  if (prevd >= 0) {
    size_t o = (size_t)prevd * 128 + c;
    if (half == 0) { sum[o] = a0; sq[o] = a1; }
    else { mx[o] = a0; mn[o] = a1; }
  }
}

// ---- post kernel: 512 thr / 8 waves, scaler-factored GEMM, fused MLP2 ------
// ALL stats select-gated by has (planes are uninitialized for deg-0 nodes).
__global__ __launch_bounds__(512, 4) void post_kernel(
    const float* __restrict__ node_feat, const int* __restrict__ deg,
    const float* __restrict__ sum, const float* __restrict__ sq,
    const float* __restrict__ mxp, const float* __restrict__ mnp,
    const short* __restrict__ Wp1T, const short* __restrict__ Wp2T,
    const float* __restrict__ b1, const float* __restrict__ b2,
    float* __restrict__ out) {
  __shared__ short Ab[2][64][64];
  __shared__ short T[64][136];
  __shared__ float scalL[64][4];
  int t = threadIdx.x;
  int lane = t & 63, w = t >> 6;
  int r15 = lane & 15, g = lane >> 4;
  int nb = blockIdx.x * 64;

  if (t < 64) {
    int n = min(nb + t, N_NODES - 1);
    float dg = (float)deg[n];
    scalL[t][0] = 1.f / fmaxf(dg, 1.f);
    float logd = logf(dg + 1.f);
    scalL[t][1] = logd * 0.4f;
    scalL[t][2] = (dg > 0.f) ? 2.5f / fmaxf(logd, 1e-5f) : 0.f;
    scalL[t][3] = (dg > 0.f) ? 1.f : 0.f;
  }
  float bb1v = b1[w * 16 + r15];

  int srow = t >> 3, s8 = t & 7;
  int sgn = min(nb + srow, N_NODES - 1);
  float4v ra, rb, qa, qb;

  auto PRE = [&](int c) {
    if (c < 2) {
      const float* np = node_feat + (size_t)sgn * 128 + c * 64 + s8 * 8;
      ra = *(const float4v*)np;
      rb = *(const float4v*)(np + 4);
    } else {
      size_t o = (size_t)sgn * 128 + (c & 1) * 64 + s8 * 8;
      int si = (c - 2) >> 1;
      if (si == 0) { ra = *(const float4v*)(sum + o); rb = *(const float4v*)(sum + o + 4); }
      else if (si == 1) { ra = *(const float4v*)(mxp + o); rb = *(const float4v*)(mxp + o + 4); }
      else if (si == 2) { ra = *(const float4v*)(mnp + o); rb = *(const float4v*)(mnp + o + 4); }
      else {
        ra = *(const float4v*)(sum + o); rb = *(const float4v*)(sum + o + 4);
        qa = *(const float4v*)(sq + o);  qb = *(const float4v*)(sq + o + 4);
      }
    }
  };
  auto WR = [&](int buf, int c) {
    short8v pk;
    if (c < 2) {
#pragma unroll
      for (int r = 0; r < 4; r++) { pk[r] = f2bf(ra[r]); pk[4 + r] = f2bf(rb[r]); }
    } else {
      int si = (c - 2) >> 1;
      float inv = scalL[srow][0];
      bool h = (scalL[srow][3] != 0.f);  // SELECT everywhere: planes uninit for deg-0
      if (si == 0) {
#pragma unroll
        for (int r = 0; r < 4; r++) {
          pk[r] = f2bf(h ? ra[r] * inv : 0.f);
          pk[4 + r] = f2bf(h ? rb[r] * inv : 0.f);
        }
      } else if (si == 1) {
#pragma unroll
        for (int r = 0; r < 4; r++) {
          pk[r] = f2bf(h ? ra[r] : 0.f);
          pk[4 + r] = f2bf(h ? rb[r] : 0.f);
        }
      } else if (si == 2) {
#pragma unroll
        for (int r = 0; r < 4; r++) {
          pk[r] = f2bf(h ? ra[r] : 0.f);
          pk[4 + r] = f2bf(h ? rb[r] : 0.f);
        }
      } else {
#pragma unroll
        for (int r = 0; r < 4; r++) {
          float m0 = ra[r] * inv, m1 = rb[r] * inv;
          float s0 = sqrtf(fmaxf(qa[r] * inv - m0 * m0, 0.f) + 1e-5f);
          float s1 = sqrtf(fmaxf(qb[r] * inv - m1 * m1, 0.f) + 1e-5f);
          pk[r] = f2bf(h ? s0 : 0.f);
          pk[4 + r] = f2bf(h ? s1 : 0.f);
        }
      }
    }
    *(short8v*)(&Ab[buf][0][0] + srow * 64 + (s8 ^ (srow & 7)) * 8) = pk;
  };

  f32x4 accB[4], accC[4], accD[4];
#pragma unroll
  for (int m = 0; m < 4; m++) {
    accB[m] = (f32x4){0.f, 0.f, 0.f, 0.f};
    accC[m] = (f32x4){0.f, 0.f, 0.f, 0.f};
    accD[m] = (f32x4){0.f, 0.f, 0.f, 0.f};
  }

  const short* wrp = Wp1T + (size_t)(w * 16 + r15) * 1664 + 8 * g;

  PRE(0);
  __syncthreads();
  WR(0, 0);
  __syncthreads();

  for (int c = 0; c < 10; c++) {
    int buf = c & 1;
    if (c < 9) PRE(c + 1);
    short8v bw0[3], bw1[3];
    if (c < 2) {
      bw0[0] = *(const short8v*)(wrp + c * 64);
      bw1[0] = *(const short8v*)(wrp + c * 64 + 32);
    } else {
      int ka = (c - 2) * 64;
      bw0[0] = *(const short8v*)(wrp + 128 + ka);
      bw0[1] = *(const short8v*)(wrp + 640 + ka);
      bw0[2] = *(const short8v*)(wrp + 1152 + ka);
      bw1[0] = *(const short8v*)(wrp + 128 + ka + 32);
      bw1[1] = *(const short8v*)(wrp + 640 + ka + 32);
      bw1[2] = *(const short8v*)(wrp + 1152 + ka + 32);
    }
    const short* base = &Ab[buf][0][0];
#pragma unroll
    for (int ks2 = 0; ks2 < 2; ks2++) {
      const short8v* bw = (ks2 == 0) ? bw0 : bw1;
      short8v af[4];
#pragma unroll
      for (int m = 0; m < 4; m++) {
        int row = m * 16 + r15;
        af[m] = *(const short8v*)(base + row * 64 + (((ks2 << 2) | g) ^ (row & 7)) * 8);
      }
      if (c < 2) {
#pragma unroll
        for (int m = 0; m < 4; m++)
          accB[m] = __builtin_amdgcn_mfma_f32_16x16x32_bf16(af[m], bw[0], accB[m], 0, 0, 0);
      } else {
#pragma unroll
        for (int m = 0; m < 4; m++) {
          accB[m] = __builtin_amdgcn_mfma_f32_16x16x32_bf16(af[m], bw[0], accB[m], 0, 0, 0);
          accC[m] = __builtin_amdgcn_mfma_f32_16x16x32_bf16(af[m], bw[1], accC[m], 0, 0, 0);
          accD[m] = __builtin_amdgcn_mfma_f32_16x16x32_bf16(af[m], bw[2], accD[m], 0, 0, 0);
        }
      }
    }
    if (c < 9) WR(buf ^ 1, c + 1);
    __syncthreads();
  }

#pragma unroll
  for (int m = 0; m < 4; m++)
#pragma unroll
    for (int r = 0; r < 4; r++) {
      int row = m * 16 + 4 * g + r;
      float v = accB[m][r] + scalL[row][1] * accC[m][r] + scalL[row][2] * accD[m][r] + bb1v;
      T[row][w * 16 + r15] = f2bf(fmaxf(v, 0.f));
    }
  __syncthreads();

  f32x4 acc2[4];
#pragma unroll
  for (int m = 0; m < 4; m++) acc2[m] = (f32x4){0.f, 0.f, 0.f, 0.f};
#pragma unroll
  for (int ks = 0; ks < 4; ks++) {
    short8v af2[4];
#pragma unroll
    for (int m = 0; m < 4; m++) af2[m] = *(const short8v*)(&T[m * 16 + r15][ks * 32 + 8 * g]);
    short8v b2f = *(const short8v*)(Wp2T + (size_t)(w * 16 + r15) * 128 + ks * 32 + 8 * g);
#pragma unroll
    for (int m = 0; m < 4; m++)
      acc2[m] = __builtin_amdgcn_mfma_f32_16x16x32_bf16(af2[m], b2f, acc2[m], 0, 0, 0);
  }

#pragma unroll
  for (int m = 0; m < 4; m++)
#pragma unroll
    for (int r = 0; r < 4; r++) {
      int row = m * 16 + 4 * g + r;
      int gn = nb + row;
      if (gn < N_NODES) {
        int col = w * 16 + r15;
        size_t o = (size_t)gn * 128 + col;
        out[o] = acc2[m][r] + b2[col] + node_feat[o];
      }
    }
}

extern "C" void kernel_launch(void* const* d_in, const int* in_sizes, int n_in,
                              void* d_out, int out_size, void* d_ws, size_t ws_size,
                              hipStream_t stream) {
  const float* node_feat = (const float*)d_in[0];
  const float* edge_feat = (const float*)d_in[1];
  const int* src = (const int*)d_in[2];
  const int* dst = (const int*)d_in[3];
  const float* W_pre = (const float*)d_in[4];
  const float* b_pre = (const float*)d_in[5];
  const float* W_post1 = (const float*)d_in[6];
  const float* b_post1 = (const float*)d_in[7];
  const float* W_post2 = (const float*)d_in[8];
  const float* b_post2 = (const float*)d_in[9];
  float* out = (float*)d_out;

  char* ws = (char*)d_ws;
  size_t P = (size_t)N_NODES * 128;
  float* sum = (float*)ws;
  float* sq = sum + P;
  float* mx = sq + P;
  float* mn = mx + P;
  int* deg = (int*)(mn + P);        // 50048
  int* cursor = deg + 50048;        // 50048
  int* rowStart = cursor + 50048;   // 50052 (N+1 + pad)
  int* blockA = rowStart + 50052;   // 3752
  int4* eid = (int4*)(blockA + 3752 + 2);  // 16B-aligned (total ints even mult of 4)
  short* UV = (short*)(eid + N_EDGES + 64);
  short* WuvT = UV + (size_t)50048 * 256;
  short* WeT = WuvT + 32768;
  short* Wp1T = WeT + 8192;
  short* Wp2T = Wp1T + 212992;
  size_t needed = (size_t)((char*)(Wp2T + 16384) - ws);
  if (ws_size < needed) return;

  conv_w_kernel<<<(270336 + 255) / 256, 256, 0, stream>>>(W_pre, W_post1, W_post2, WuvT, WeT,
                                                          Wp1T, Wp2T, deg);
  deg_kernel<<<1024, 256, 0, stream>>>(dst, deg);
  scan_kernel<<<1, 1024, 0, stream>>>(deg, cursor, rowStart);
  scatter_kernel<<<1024, 256, 0, stream>>>(src, dst, cursor, rowStart, eid, blockA);
  uv_kernel<<<(N_NODES + 63) / 64, 256, 0, stream>>>(node_feat, WuvT, UV);
  edge_kernel<<<EG, 256, 0, stream>>>(eid, blockA, edge_feat, b_pre, UV, WeT, sum, sq, mx, mn);
  post_kernel<<<(N_NODES + 63) / 64, 512, 0, stream>>>(node_feat, deg, sum, sq, mx, mn, Wp1T,
                                                       Wp2T, b_post1, b_post2, out);
}

// Round 11
// 288.250 us; speedup vs baseline: 1.4176x; 1.4176x over previous
//
#include <hip/hip_runtime.h>
#include <hip/hip_bf16.h>
#include <math.h>

#define N_NODES 50000
#define N_EDGES 600000
#define EG 3750   // edge-kernel grid; blockA has EG+1 node-aligned edge offsets
#define SCAN_NB 196  // 196*256 = 50176 >= N_NODES
// IN_DIM=128, EDGE_DIM=64; e = relu(U[src] + V[dst] + ef@We + b_pre)

typedef __attribute__((ext_vector_type(8))) short short8v;   // 8 bf16 MFMA A/B frag
typedef __attribute__((ext_vector_type(4))) short short4v;
typedef __attribute__((ext_vector_type(4))) float f32x4;     // MFMA C/D frag
typedef __attribute__((ext_vector_type(4))) float float4v;

#define FLT_BIG 3.402823466e38f

__device__ __forceinline__ short f2bf(float f) {
  unsigned int u = __float_as_uint(f);
  u = (u + 0x7FFFu + ((u >> 16) & 1u)) >> 16;   // RNE
  return (short)u;
}
__device__ __forceinline__ float bf2f(unsigned short s) {
  return __uint_as_float(((unsigned int)s) << 16);
}

// ---- weights (+ deg zeroing): WuvT[256][128], WeT[128][64], Wp1T, Wp2T -----
__global__ void conv_w_kernel(const float* __restrict__ Wpre, const float* __restrict__ Wp1,
                              const float* __restrict__ Wp2, short* __restrict__ WuvT,
                              short* __restrict__ WeT, short* __restrict__ Wp1T,
                              short* __restrict__ Wp2T, int* __restrict__ deg) {
  int idx = blockIdx.x * 256 + threadIdx.x;
  if (idx < 50048) deg[idx] = 0;
  if (idx < 32768) {                       // WuvT: row c (<128:U, >=128:V), col k
    int c = idx >> 7, k = idx & 127;
    WuvT[idx] = f2bf(Wpre[(k + ((c >> 7) << 7)) * 128 + (c & 127)]);
  } else if (idx < 40960) {                // WeT
    int o = idx - 32768, n = o >> 6, k = o & 63;
    WeT[o] = f2bf(Wpre[(256 + k) * 128 + n]);
  } else if (idx < 253952) {               // Wp1T
    int o = idx - 40960, n = o / 1664, k = o % 1664;
    Wp1T[o] = f2bf(Wp1[k * 128 + n]);
  } else if (idx < 270336) {               // Wp2T
    int o = idx - 253952, n = o >> 7, k = o & 127;
    Wp2T[o] = f2bf(Wp2[k * 128 + n]);
  }
}

// ---- degree histogram ------------------------------------------------------
__global__ void deg_kernel(const int* __restrict__ dst, int* __restrict__ deg) {
  int i = blockIdx.x * blockDim.x + threadIdx.x;
  int stride = gridDim.x * blockDim.x;
  for (; i < N_EDGES; i += stride) atomicAdd(deg + dst[i], 1);
}

// ---- parallel exclusive scan, 3 phases (was 126us single-block serial) -----
__global__ __launch_bounds__(256) void scan1_kernel(const int* __restrict__ deg,
                                                    int* __restrict__ blockSums) {
  __shared__ int red[256];
  int b = blockIdx.x, t = threadIdx.x;
  int n = b * 256 + t;
  red[t] = (n < N_NODES) ? deg[n] : 0;
  __syncthreads();
  for (int off = 128; off > 0; off >>= 1) {
    if (t < off) red[t] += red[t + off];
    __syncthreads();
  }
  if (t == 0) blockSums[b] = red[0];
}

__global__ __launch_bounds__(256) void scan2_kernel(const int* __restrict__ blockSums,
                                                    int* __restrict__ blockOffs) {
  __shared__ int sh[256];
  int t = threadIdx.x;
  int v = (t < SCAN_NB) ? blockSums[t] : 0;
  sh[t] = v;
  __syncthreads();
  for (int off = 1; off < 256; off <<= 1) {
    int u = (t >= off) ? sh[t - off] : 0;
    __syncthreads();
    sh[t] += u;
    __syncthreads();
  }
  if (t < SCAN_NB) blockOffs[t] = sh[t] - v;  // exclusive
}

__global__ __launch_bounds__(256) void scan3_kernel(const int* __restrict__ deg,
                                                    const int* __restrict__ blockOffs,
                                                    int* __restrict__ cursor,
                                                    int* __restrict__ rowStart) {
  __shared__ int sh[256];
  int b = blockIdx.x, t = threadIdx.x;
  int n = b * 256 + t;
  int v = (n < N_NODES) ? deg[n] : 0;
  sh[t] = v;
  __syncthreads();
  for (int off = 1; off < 256; off <<= 1) {
    int u = (t >= off) ? sh[t - off] : 0;
    __syncthreads();
    sh[t] += u;
    __syncthreads();
  }
  int ex = blockOffs[b] + sh[t] - v;
  if (n < N_NODES) { cursor[n] = ex; rowStart[n] = ex; }
  if (n == N_NODES) rowStart[N_NODES] = N_EDGES;
}

// ---- scatter: eid int4{perm,src,dst,0} + node-aligned block ranges ---------
__global__ void scatter_kernel(const int* __restrict__ src, const int* __restrict__ dst,
                               int* __restrict__ cursor, const int* __restrict__ rowStart,
                               int4* __restrict__ eid, int* __restrict__ blockA) {
  int i0 = blockIdx.x * blockDim.x + threadIdx.x;
  int stride = gridDim.x * blockDim.x;
  for (int i = i0; i < N_EDGES; i += stride) {
    int d = dst[i];
    int pos = atomicAdd(cursor + d, 1);
    eid[pos] = make_int4(i, src[i], d, 0);
  }
  for (int j = N_EDGES + i0; j < N_EDGES + 64; j += stride)
    eid[j] = make_int4(0, 0, 0, 0);  // safe tail for clamped prefetch
  for (int b = i0; b <= EG; b += stride) {
    int tgt = (int)((long)b * N_EDGES / EG);
    int lo = 0, hi = N_NODES;
    while (lo < hi) { int mid = (lo + hi) >> 1; if (rowStart[mid] < tgt) lo = mid + 1; else hi = mid; }
    blockA[b] = rowStart[lo];   // node-aligned; rowStart[N]=E sentinel
  }
}

// ---- UV kernel: [U|V] = x @ [Ws|Wd], dense 50K x 128 -> 256, bf16 out ------
__global__ __launch_bounds__(256) void uv_kernel(const float* __restrict__ nf,
                                                 const short* __restrict__ WuvT,
                                                 short* __restrict__ UV) {
  __shared__ short A[64][136];
  int t = threadIdx.x;
  int lane = t & 63, w = t >> 6;
  int r15 = lane & 15, g = lane >> 4;
  int nb = blockIdx.x * 64;

#pragma unroll
  for (int i = 0; i < 8; i++) {
    int u = t + 256 * i, row = u >> 5, q = u & 31;
    int gn = min(nb + row, N_NODES - 1);
    float4v a = *(const float4v*)(nf + (size_t)gn * 128 + q * 4);
    short4v s;
    s[0] = f2bf(a[0]); s[1] = f2bf(a[1]); s[2] = f2bf(a[2]); s[3] = f2bf(a[3]);
    *(short4v*)(&A[row][q * 4]) = s;
  }
  __syncthreads();

  f32x4 acc[4][4];
#pragma unroll
  for (int m = 0; m < 4; m++)
#pragma unroll
    for (int j = 0; j < 4; j++) acc[m][j] = (f32x4){0.f, 0.f, 0.f, 0.f};

#pragma unroll
  for (int ks = 0; ks < 4; ks++) {
    short8v af[4];
#pragma unroll
    for (int m = 0; m < 4; m++) af[m] = *(const short8v*)(&A[m * 16 + r15][ks * 32 + 8 * g]);
#pragma unroll
    for (int j = 0; j < 4; j++) {
      short8v bf = *(const short8v*)(WuvT + (size_t)((4 * w + j) * 16 + r15) * 128 + ks * 32 + 8 * g);
#pragma unroll
      for (int m = 0; m < 4; m++)
        acc[m][j] = __builtin_amdgcn_mfma_f32_16x16x32_bf16(af[m], bf, acc[m][j], 0, 0, 0);
    }
  }

#pragma unroll
  for (int m = 0; m < 4; m++)
#pragma unroll
    for (int j = 0; j < 4; j++)
#pragma unroll
      for (int r = 0; r < 4; r++) {
        int node = nb + m * 16 + 4 * g + r;
        if (node < N_NODES)
          UV[(size_t)node * 256 + (4 * w + j) * 16 + r15] = f2bf(acc[m][j][r]);
      }
}

// ---- edge kernel: node-aligned block ranges, carry accumulators across -----
// chunks, ALL flushes plain stores (no atomics, no plane init needed).
__global__ __launch_bounds__(256, 6) void edge_kernel(
    const int4* __restrict__ eid, const int* __restrict__ blockA,
    const float* __restrict__ edge_feat, const float* __restrict__ b_pre,
    const short* __restrict__ UV, const short* __restrict__ WeT,
    float* __restrict__ sum, float* __restrict__ sq,
    float* __restrict__ mx, float* __restrict__ mn) {
  __shared__ short A[32][72];        // 32 edges x 64 k (pad 8)
  __shared__ float E[32][132];       // F, then in-place e (pad 4)
  __shared__ int srcL[2][32], dstL[2][32];

  int t = threadIdx.x;
  int lane = t & 63, w = t >> 6;
  int r15 = lane & 15, g = lane >> 4;

  short8v bfr[2][2];
#pragma unroll
  for (int ks = 0; ks < 2; ks++)
#pragma unroll
    for (int j = 0; j < 2; j++)
      bfr[ks][j] = *(const short8v*)(WeT + (size_t)((2 * w + j) * 16 + r15) * 64 + ks * 32 + 8 * g);

  int c = t & 127, half = t >> 7;    // scan role: col, stat-pair
  int cd = t & 63, wrow = t >> 6;    // compose role: col-pair, row-group
  float bp0 = b_pre[2 * cd], bp1 = b_pre[2 * cd + 1];

  const unsigned short* UVu = (const unsigned short*)UV;
  int A0 = blockA[blockIdx.x], A1 = blockA[blockIdx.x + 1];
  if (A0 >= A1) return;

  float4v ge[2];
  auto LOADE = [&](int e0c) {
#pragma unroll
    for (int i = 0; i < 2; i++) {
      int u = t + 256 * i, e = u >> 4, q = u & 15;
      int pe = eid[min(e0c + e, N_EDGES + 63)].x;
      ge[i] = *(const float4v*)(edge_feat + (size_t)pe * 64 + q * 4);
    }
  };
  auto WRITE_A = [&]() {
#pragma unroll
    for (int i = 0; i < 2; i++) {
      int u = t + 256 * i, e = u >> 4, q = u & 15;
      short4v s4;
      s4[0] = f2bf(ge[i][0]); s4[1] = f2bf(ge[i][1]);
      s4[2] = f2bf(ge[i][2]); s4[3] = f2bf(ge[i][3]);
      *(short4v*)(&A[e][q * 4]) = s4;
    }
  };
  int nsrc = 0, ndst = 0;
  auto IDXLOAD = [&](int e0c) {
    if (t < 32) {
      int4 v = eid[min(e0c + t, N_EDGES + 63)];
      nsrc = v.y; ndst = v.z;
    }
  };

  // prologue
  LOADE(A0);
  IDXLOAD(A0);
  if (t < 32) { srcL[0][t] = nsrc; dstL[0][t] = ndst; }
  WRITE_A();
  IDXLOAD(A0 + 32);
  __syncthreads();

  // carried segment state (node-aligned ownership -> plain stores only)
  float a0 = (half == 0) ? 0.f : -FLT_BIG;
  float a1 = (half == 0) ? 0.f : FLT_BIG;
  int prevd = -1;

  int p = 0;
  for (int e0 = A0; e0 < A1; e0 += 32) {
    int cnt = min(32, A1 - e0);
    // ==== P1: whole-chunk UV prefetch; MFMA F; issue next gathers ====
    unsigned int upf[8], vpf[8];
#pragma unroll
    for (int i = 0; i < 8; i++) {
      int rr = min(wrow + 4 * i, cnt - 1);
      int sr = srcL[p][rr], dr = dstL[p][rr];
      upf[i] = *(const unsigned int*)(UVu + (size_t)sr * 256 + 2 * cd);
      vpf[i] = *(const unsigned int*)(UVu + (size_t)dr * 256 + 128 + 2 * cd);
    }
    LOADE(e0 + 32);

    f32x4 acc[2][2];
#pragma unroll
    for (int m = 0; m < 2; m++)
#pragma unroll
      for (int j = 0; j < 2; j++) acc[m][j] = (f32x4){0.f, 0.f, 0.f, 0.f};
#pragma unroll
    for (int m = 0; m < 2; m++)
#pragma unroll
      for (int ks = 0; ks < 2; ks++) {
        short8v af = *(const short8v*)(&A[m * 16 + r15][ks * 32 + 8 * g]);
        acc[m][0] = __builtin_amdgcn_mfma_f32_16x16x32_bf16(af, bfr[ks][0], acc[m][0], 0, 0, 0);
        acc[m][1] = __builtin_amdgcn_mfma_f32_16x16x32_bf16(af, bfr[ks][1], acc[m][1], 0, 0, 0);
      }
#pragma unroll
    for (int m = 0; m < 2; m++)
#pragma unroll
      for (int j = 0; j < 2; j++)
#pragma unroll
        for (int r = 0; r < 4; r++)
          E[m * 16 + 4 * g + r][(2 * w + j) * 16 + r15] = acc[m][j][r];
    __syncthreads();  // B1

    // ==== P2a: e = relu(u + v + F + b) in place ====
#pragma unroll
    for (int i = 0; i < 8; i++) {
      int r = wrow + 4 * i;
      float u0 = bf2f((unsigned short)(upf[i] & 0xFFFFu));
      float u1 = bf2f((unsigned short)(upf[i] >> 16));
      float v0 = bf2f((unsigned short)(vpf[i] & 0xFFFFu));
      float v1 = bf2f((unsigned short)(vpf[i] >> 16));
      E[r][2 * cd] = fmaxf(u0 + v0 + E[r][2 * cd] + bp0, 0.f);
      E[r][2 * cd + 1] = fmaxf(u1 + v1 + E[r][2 * cd + 1] + bp1, 0.f);
    }
    __syncthreads();  // B2

    // ==== P2b: carried segmented scan, plain stores; stage next chunk ====
    {
      int l = lane & 31;
      int dl_ = dstL[p][l];
      int dp_ = (l == 0) ? prevd : dstL[p][l - 1];
      unsigned int bm = (unsigned int)__ballot(dl_ != dp_);
#pragma unroll
      for (int r = 0; r < 32; r++) {
        if (r < cnt) {  // uniform
          if ((bm >> r) & 1u) {  // wave-uniform
            int tgt = (r == 0) ? prevd : dstL[p][r - 1];
            if (tgt >= 0) {
              size_t o = (size_t)tgt * 128 + c;
              if (half == 0) { sum[o] = a0; sq[o] = a1; }
              else { mx[o] = a0; mn[o] = a1; }
            }
            if (half == 0) { a0 = 0.f; a1 = 0.f; }
            else { a0 = -FLT_BIG; a1 = FLT_BIG; }
          }
          float e = E[r][c];
          if (half == 0) { a0 += e; a1 += e * e; }
          else { a0 = fmaxf(a0, e); a1 = fminf(a1, e); }
        }
      }
      prevd = dstL[p][cnt - 1];
    }
    WRITE_A();
    if (t < 32) { srcL[p ^ 1][t] = nsrc; dstL[p ^ 1][t] = ndst; }
    IDXLOAD(e0 + 64);
    __syncthreads();  // B3
    p ^= 1;
  }
  // final flush of carried segment (block owns this node exclusively)
  if (prevd >= 0) {
    size_t o = (size_t)prevd * 128 + c;
    if (half == 0) { sum[o] = a0; sq[o] = a1; }
    else { mx[o] = a0; mn[o] = a1; }
  }
}

// ---- post kernel: 512 thr / 8 waves, scaler-factored GEMM, fused MLP2 ------
// ALL stats select-gated by has (planes are uninitialized for deg-0 nodes).
__global__ __launch_bounds__(512, 4) void post_kernel(
    const float* __restrict__ node_feat, const int* __restrict__ deg,
    const float* __restrict__ sum, const float* __restrict__ sq,
    const float* __restrict__ mxp, const float* __restrict__ mnp,
    const short* __restrict__ Wp1T, const short* __restrict__ Wp2T,
    const float* __restrict__ b1, const float* __restrict__ b2,
    float* __restrict__ out) {
  __shared__ short Ab[2][64][64];
  __shared__ short T[64][136];
  __shared__ float scalL[64][4];
  int t = threadIdx.x;
  int lane = t & 63, w = t >> 6;
  int r15 = lane & 15, g = lane >> 4;
  int nb = blockIdx.x * 64;

  if (t < 64) {
    int n = min(nb + t, N_NODES - 1);
    float dg = (float)deg[n];
    scalL[t][0] = 1.f / fmaxf(dg, 1.f);
    float logd = logf(dg + 1.f);
    scalL[t][1] = logd * 0.4f;
    scalL[t][2] = (dg > 0.f) ? 2.5f / fmaxf(logd, 1e-5f) : 0.f;
    scalL[t][3] = (dg > 0.f) ? 1.f : 0.f;
  }
  float bb1v = b1[w * 16 + r15];

  int srow = t >> 3, s8 = t & 7;
  int sgn = min(nb + srow, N_NODES - 1);
  float4v ra, rb, qa, qb;

  auto PRE = [&](int c) {
    if (c < 2) {
      const float* np = node_feat + (size_t)sgn * 128 + c * 64 + s8 * 8;
      ra = *(const float4v*)np;
      rb = *(const float4v*)(np + 4);
    } else {
      size_t o = (size_t)sgn * 128 + (c & 1) * 64 + s8 * 8;
      int si = (c - 2) >> 1;
      if (si == 0) { ra = *(const float4v*)(sum + o); rb = *(const float4v*)(sum + o + 4); }
      else if (si == 1) { ra = *(const float4v*)(mxp + o); rb = *(const float4v*)(mxp + o + 4); }
      else if (si == 2) { ra = *(const float4v*)(mnp + o); rb = *(const float4v*)(mnp + o + 4); }
      else {
        ra = *(const float4v*)(sum + o); rb = *(const float4v*)(sum + o + 4);
        qa = *(const float4v*)(sq + o);  qb = *(const float4v*)(sq + o + 4);
      }
    }
  };
  auto WR = [&](int buf, int c) {
    short8v pk;
    if (c < 2) {
#pragma unroll
      for (int r = 0; r < 4; r++) { pk[r] = f2bf(ra[r]); pk[4 + r] = f2bf(rb[r]); }
    } else {
      int si = (c - 2) >> 1;
      float inv = scalL[srow][0];
      bool h = (scalL[srow][3] != 0.f);  // SELECT everywhere: planes uninit for deg-0
      if (si == 0) {
#pragma unroll
        for (int r = 0; r < 4; r++) {
          pk[r] = f2bf(h ? ra[r] * inv : 0.f);
          pk[4 + r] = f2bf(h ? rb[r] * inv : 0.f);
        }
      } else if (si == 1) {
#pragma unroll
        for (int r = 0; r < 4; r++) {
          pk[r] = f2bf(h ? ra[r] : 0.f);
          pk[4 + r] = f2bf(h ? rb[r] : 0.f);
        }
      } else if (si == 2) {
#pragma unroll
        for (int r = 0; r < 4; r++) {
          pk[r] = f2bf(h ? ra[r] : 0.f);
          pk[4 + r] = f2bf(h ? rb[r] : 0.f);
        }
      } else {
#pragma unroll
        for (int r = 0; r < 4; r++) {
          float m0 = ra[r] * inv, m1 = rb[r] * inv;
          float s0 = sqrtf(fmaxf(qa[r] * inv - m0 * m0, 0.f) + 1e-5f);
          float s1 = sqrtf(fmaxf(qb[r] * inv - m1 * m1, 0.f) + 1e-5f);
          pk[r] = f2bf(h ? s0 : 0.f);
          pk[4 + r] = f2bf(h ? s1 : 0.f);
        }
      }
    }
    *(short8v*)(&Ab[buf][0][0] + srow * 64 + (s8 ^ (srow & 7)) * 8) = pk;
  };

  f32x4 accB[4], accC[4], accD[4];
#pragma unroll
  for (int m = 0; m < 4; m++) {
    accB[m] = (f32x4){0.f, 0.f, 0.f, 0.f};
    accC[m] = (f32x4){0.f, 0.f, 0.f, 0.f};
    accD[m] = (f32x4){0.f, 0.f, 0.f, 0.f};
  }

  const short* wrp = Wp1T + (size_t)(w * 16 + r15) * 1664 + 8 * g;

  PRE(0);
  __syncthreads();
  WR(0, 0);
  __syncthreads();

  for (int c = 0; c < 10; c++) {
    int buf = c & 1;
    if (c < 9) PRE(c + 1);
    short8v bw0[3], bw1[3];
    if (c < 2) {
      bw0[0] = *(const short8v*)(wrp + c * 64);
      bw1[0] = *(const short8v*)(wrp + c * 64 + 32);
    } else {
      int ka = (c - 2) * 64;
      bw0[0] = *(const short8v*)(wrp + 128 + ka);
      bw0[1] = *(const short8v*)(wrp + 640 + ka);
      bw0[2] = *(const short8v*)(wrp + 1152 + ka);
      bw1[0] = *(const short8v*)(wrp + 128 + ka + 32);
      bw1[1] = *(const short8v*)(wrp + 640 + ka + 32);
      bw1[2] = *(const short8v*)(wrp + 1152 + ka + 32);
    }
    const short* base = &Ab[buf][0][0];
#pragma unroll
    for (int ks2 = 0; ks2 < 2; ks2++) {
      const short8v* bw = (ks2 == 0) ? bw0 : bw1;
      short8v af[4];
#pragma unroll
      for (int m = 0; m < 4; m++) {
        int row = m * 16 + r15;
        af[m] = *(const short8v*)(base + row * 64 + (((ks2 << 2) | g) ^ (row & 7)) * 8);
      }
      if (c < 2) {
#pragma unroll
        for (int m = 0; m < 4; m++)
          accB[m] = __builtin_amdgcn_mfma_f32_16x16x32_bf16(af[m], bw[0], accB[m], 0, 0, 0);
      } else {
#pragma unroll
        for (int m = 0; m < 4; m++) {
          accB[m] = __builtin_amdgcn_mfma_f32_16x16x32_bf16(af[m], bw[0], accB[m], 0, 0, 0);
          accC[m] = __builtin_amdgcn_mfma_f32_16x16x32_bf16(af[m], bw[1], accC[m], 0, 0, 0);
          accD[m] = __builtin_amdgcn_mfma_f32_16x16x32_bf16(af[m], bw[2], accD[m], 0, 0, 0);
        }
      }
    }
    if (c < 9) WR(buf ^ 1, c + 1);
    __syncthreads();
  }

#pragma unroll
  for (int m = 0; m < 4; m++)
#pragma unroll
    for (int r = 0; r < 4; r++) {
      int row = m * 16 + 4 * g + r;
      float v = accB[m][r] + scalL[row][1] * accC[m][r] + scalL[row][2] * accD[m][r] + bb1v;
      T[row][w * 16 + r15] = f2bf(fmaxf(v, 0.f));
    }
  __syncthreads();

  f32x4 acc2[4];
#pragma unroll
  for (int m = 0; m < 4; m++) acc2[m] = (f32x4){0.f, 0.f, 0.f, 0.f};
#pragma unroll
  for (int ks = 0; ks < 4; ks++) {
    short8v af2[4];
#pragma unroll
    for (int m = 0; m < 4; m++) af2[m] = *(const short8v*)(&T[m * 16 + r15][ks * 32 + 8 * g]);
    short8v b2f = *(const short8v*)(Wp2T + (size_t)(w * 16 + r15) * 128 + ks * 32 + 8 * g);
#pragma unroll
    for (int m = 0; m < 4; m++)
      acc2[m] = __builtin_amdgcn_mfma_f32_16x16x32_bf16(af2[m], b2f, acc2[m], 0, 0, 0);
  }

#pragma unroll
  for (int m = 0; m < 4; m++)
#pragma unroll
    for (int r = 0; r < 4; r++) {
      int row = m * 16 + 4 * g + r;
      int gn = nb + row;
      if (gn < N_NODES) {
        int col = w * 16 + r15;
        size_t o = (size_t)gn * 128 + col;
        out[o] = acc2[m][r] + b2[col] + node_feat[o];
      }
    }
}

extern "C" void kernel_launch(void* const* d_in, const int* in_sizes, int n_in,
                              void* d_out, int out_size, void* d_ws, size_t ws_size,
                              hipStream_t stream) {
  const float* node_feat = (const float*)d_in[0];
  const float* edge_feat = (const float*)d_in[1];
  const int* src = (const int*)d_in[2];
  const int* dst = (const int*)d_in[3];
  const float* W_pre = (const float*)d_in[4];
  const float* b_pre = (const float*)d_in[5];
  const float* W_post1 = (const float*)d_in[6];
  const float* b_post1 = (const float*)d_in[7];
  const float* W_post2 = (const float*)d_in[8];
  const float* b_post2 = (const float*)d_in[9];
  float* out = (float*)d_out;

  char* ws = (char*)d_ws;
  size_t P = (size_t)N_NODES * 128;
  float* sum = (float*)ws;
  float* sq = sum + P;
  float* mx = sq + P;
  float* mn = mx + P;
  int* deg = (int*)(mn + P);        // 50048
  int* cursor = deg + 50048;        // 50048
  int* rowStart = cursor + 50048;   // 50052
  int* blockA = rowStart + 50052;   // 3752
  int* blockSums = blockA + 3752;   // 256
  int* blockOffs = blockSums + 256; // 256  -> total 154412 ints = 617648 B (16B-aligned)
  int4* eid = (int4*)(blockOffs + 256);
  short* UV = (short*)(eid + N_EDGES + 64);
  short* WuvT = UV + (size_t)50048 * 256;
  short* WeT = WuvT + 32768;
  short* Wp1T = WeT + 8192;
  short* Wp2T = Wp1T + 212992;
  size_t needed = (size_t)((char*)(Wp2T + 16384) - ws);
  if (ws_size < needed) return;

  conv_w_kernel<<<(270336 + 255) / 256, 256, 0, stream>>>(W_pre, W_post1, W_post2, WuvT, WeT,
                                                          Wp1T, Wp2T, deg);
  deg_kernel<<<1024, 256, 0, stream>>>(dst, deg);
  scan1_kernel<<<SCAN_NB, 256, 0, stream>>>(deg, blockSums);
  scan2_kernel<<<1, 256, 0, stream>>>(blockSums, blockOffs);
  scan3_kernel<<<SCAN_NB, 256, 0, stream>>>(deg, blockOffs, cursor, rowStart);
  scatter_kernel<<<1024, 256, 0, stream>>>(src, dst, cursor, rowStart, eid, blockA);
  uv_kernel<<<(N_NODES + 63) / 64, 256, 0, stream>>>(node_feat, WuvT, UV);
  edge_kernel<<<EG, 256, 0, stream>>>(eid, blockA, edge_feat, b_pre, UV, WeT, sum, sq, mx, mn);
  post_kernel<<<(N_NODES + 63) / 64, 512, 0, stream>>>(node_feat, deg, sum, sq, mx, mn, Wp1T,
                                                       Wp2T, b_post1, b_post2, out);
}